// Round 2
// baseline (875.633 us; speedup 1.0000x reference)
//
#include <hip/hip_runtime.h>
#include <hip/hip_bf16.h>

typedef __bf16 bf16x8 __attribute__((ext_vector_type(8)));
typedef float f32x4 __attribute__((ext_vector_type(4)));
using bf16 = __hip_bfloat16;

constexpr int T = 2048;
constexpr int D = 128;
constexpr int M = 8 * 2048;   // B*T rows
constexpr int LDA = 136;      // 128 + 8 bf16 pad

// flag-aware scalar load: input may be float32 or bf16, decided at runtime
__device__ inline float ldf(const void* p, size_t i, int isf32) {
  if (isf32) return ((const float*)p)[i];
  unsigned u = ((const unsigned short*)p)[i];
  return __uint_as_float(u << 16);
}

// ---------------- dtype probe + param conversion ----------------
struct PPtrs { const void* p[12]; };

__global__ void detect_convert_k(const void* __restrict__ item, PPtrs ps,
                                 float* __restrict__ params, int* __restrict__ flagp) {
  __shared__ int cnt[4];
  __shared__ int flagLDS;
  int tid = threadIdx.x;
  // probe: low 16 bits of the first 256 "elements". bf16 data -> plausible small
  // bf16 values; f32 data -> random mantissa bits -> implausible bf16.
  unsigned short lo = ((const unsigned short*)item)[tid * 2];
  float bv = __uint_as_float((unsigned)lo << 16);
  float a = fabsf(bv);
  bool okb = (a > 1e-5f) && (a < 0.5f);
  unsigned long long m = __ballot(okb);
  if ((tid & 63) == 0) cnt[tid >> 6] = __popcll(m);
  __syncthreads();
  if (tid == 0) {
    int tot = cnt[0] + cnt[1] + cnt[2] + cnt[3];
    int f = (tot < 128) ? 1 : 0;  // 1 = inputs are float32
    flagLDS = f;
    *flagp = f;
  }
  __syncthreads();
  int f = flagLDS;
  const int lens[12] = {128, 512, 512, 512, 128, 512, 512, 512, 512, 512, 512, 512};
  int off = 0;
  for (int j = 0; j < 12; ++j) {
    for (int i = tid; i < lens[j]; i += 256) params[off + i] = ldf(ps.p[j], i, f);
    off += lens[j];
  }
}

// ---------------- weight transpose: W[K][N] -> WT[N][K] (canonical bf16) ----------------
struct WPtrs { const void* p[7]; };

__global__ void transpose_w_k(WPtrs w, bf16* __restrict__ dst, const int* __restrict__ flagp) {
  int f = *flagp;
  int l = blockIdx.x, wi = blockIdx.y;
  const void* s = (const void*)((const char*)w.p[wi]);
  size_t sbase = (size_t)l * 16384;
  bf16* d = dst + ((size_t)wi * 4 + l) * 16384;
  for (int i = 0; i < 64; ++i) {
    int e = i * 256 + threadIdx.x;                       // e = n*128 + k
    d[e] = __float2bfloat16(ldf(s, sbase + (size_t)(e & 127) * 128 + (e >> 7), f));
  }
}

// ---------------- embedding gather + RMSNorm -> x fp32 ----------------
__global__ void embed_rms_k(const int* __restrict__ seqs, const void* __restrict__ item,
                            const void* __restrict__ pos, const float* __restrict__ scale,
                            float* __restrict__ x, const int* __restrict__ flagp) {
  int f = *flagp;
  int row = blockIdx.x * 4 + (threadIdx.x >> 6);  // one wave per row
  int lane = threadIdx.x & 63;
  int t = row & (T - 1);
  int idx = seqs[row];
  int c = lane * 2;
  float e0 = ldf(item, (size_t)idx * D + c, f)     + ldf(pos, (size_t)(t + 1) * D + c, f);
  float e1 = ldf(item, (size_t)idx * D + c + 1, f) + ldf(pos, (size_t)(t + 1) * D + c + 1, f);
  float ss = e0 * e0 + e1 * e1;
  #pragma unroll
  for (int off = 32; off; off >>= 1) ss += __shfl_xor(ss, off);
  float rs = rsqrtf(ss * (1.f / 128.f) + 1e-8f);
  float* xr = x + (size_t)row * D + c;
  xr[0] = e0 * rs * scale[c];
  xr[1] = e1 * rs * scale[c + 1];
}

// ---------------- RMSNorm (x fp32 -> bf16), optional elementwise mul ----------------
__global__ void rms_k(const float* __restrict__ x, const float* __restrict__ scale,
                      const bf16* __restrict__ mul, bf16* __restrict__ out) {
  int row = blockIdx.x * 4 + (threadIdx.x >> 6);
  int lane = threadIdx.x & 63;
  int c = lane * 2;
  float2 v = *reinterpret_cast<const float2*>(x + (size_t)row * D + c);
  float ss = v.x * v.x + v.y * v.y;
  #pragma unroll
  for (int off = 32; off; off >>= 1) ss += __shfl_xor(ss, off);
  float rs = rsqrtf(ss * (1.f / 128.f) + 1e-8f);
  float o0 = v.x * rs * scale[c];
  float o1 = v.y * rs * scale[c + 1];
  if (mul) {
    __hip_bfloat162 mv = *reinterpret_cast<const __hip_bfloat162*>(mul + (size_t)row * D + c);
    o0 *= __bfloat162float(mv.x);
    o1 *= __bfloat162float(mv.y);
  }
  __hip_bfloat162 ov;
  ov.x = __float2bfloat16(o0); ov.y = __float2bfloat16(o1);
  *reinterpret_cast<__hip_bfloat162*>(out + (size_t)row * D + c) = ov;
}

// ---------------- final RMSNorm -> d_out (dtype per flag) ----------------
__global__ void rms_out_k(const float* __restrict__ x, const float* __restrict__ scale,
                          void* __restrict__ out, const int* __restrict__ flagp) {
  int row = blockIdx.x * 4 + (threadIdx.x >> 6);
  int lane = threadIdx.x & 63;
  int c = lane * 2;
  float2 v = *reinterpret_cast<const float2*>(x + (size_t)row * D + c);
  float ss = v.x * v.x + v.y * v.y;
  #pragma unroll
  for (int off = 32; off; off >>= 1) ss += __shfl_xor(ss, off);
  float rs = rsqrtf(ss * (1.f / 128.f) + 1e-8f);
  float o0 = v.x * rs * scale[c];
  float o1 = v.y * rs * scale[c + 1];
  if (*flagp) {
    float2 ov; ov.x = o0; ov.y = o1;
    *reinterpret_cast<float2*>((float*)out + (size_t)row * D + c) = ov;
  } else {
    __hip_bfloat162 ov;
    ov.x = __float2bfloat16(o0); ov.y = __float2bfloat16(o1);
    *reinterpret_cast<__hip_bfloat162*>((bf16*)out + (size_t)row * D + c) = ov;
  }
}

// ---------------- GEMM: C[M x 128] = act(A[M x 128] @ W + bias) ----------------
// mode 0: silu -> bf16 out; mode 1: gelu(exact) -> bf16 out; mode 2: resid fp32 += C
__global__ __launch_bounds__(256) void gemm_k(
    const bf16* __restrict__ A, const bf16* __restrict__ WT, const float* __restrict__ bias,
    bf16* __restrict__ out, float* __restrict__ resid, int mode) {
  __shared__ __align__(16) bf16 la[64 * LDA];
  __shared__ __align__(16) bf16 lb[64 * LDA];
  int tid = threadIdx.x;
  int m0 = blockIdx.x * 64, n0 = blockIdx.y * 64;
  #pragma unroll
  for (int i = 0; i < 4; ++i) {
    int ch = i * 256 + tid, r = ch >> 4, c = ch & 15;
    *reinterpret_cast<uint4*>(&la[r * LDA + c * 8]) =
        *reinterpret_cast<const uint4*>(A + (size_t)(m0 + r) * D + c * 8);
    *reinterpret_cast<uint4*>(&lb[r * LDA + c * 8]) =
        *reinterpret_cast<const uint4*>(WT + (size_t)(n0 + r) * D + c * 8);
  }
  __syncthreads();
  int wave = tid >> 6, lane = tid & 63, quad = lane >> 4, l16 = lane & 15;
  f32x4 acc[4] = {};
  #pragma unroll
  for (int kk = 0; kk < 4; ++kk) {
    bf16x8 a = *reinterpret_cast<const bf16x8*>(&la[(wave * 16 + l16) * LDA + kk * 32 + quad * 8]);
    #pragma unroll
    for (int nt = 0; nt < 4; ++nt) {
      bf16x8 b = *reinterpret_cast<const bf16x8*>(&lb[(nt * 16 + l16) * LDA + kk * 32 + quad * 8]);
      acc[nt] = __builtin_amdgcn_mfma_f32_16x16x32_bf16(a, b, acc[nt], 0, 0, 0);
    }
  }
  int rbase = m0 + wave * 16 + quad * 4;
  #pragma unroll
  for (int nt = 0; nt < 4; ++nt) {
    int col = n0 + nt * 16 + l16;
    float bv = bias[col];
    #pragma unroll
    for (int r = 0; r < 4; ++r) {
      float v = acc[nt][r] + bv;
      size_t off = (size_t)(rbase + r) * D + col;
      if (mode == 0) {
        v = v / (1.f + __expf(-v));
        out[off] = __float2bfloat16(v);
      } else if (mode == 1) {
        v = 0.5f * v * (1.f + erff(v * 0.70710678118f));
        out[off] = __float2bfloat16(v);
      } else {
        resid[off] += v;
      }
    }
  }
}

// ---------------- HSTU flash attention ----------------
__global__ __launch_bounds__(256) void flash_k(const bf16* __restrict__ Qb,
    const bf16* __restrict__ Kb, const bf16* __restrict__ Vb, float* __restrict__ AV) {
  int mt = blockIdx.x, bh = blockIdx.y;
  int b = bh >> 1, h = bh & 1;
  int tid = threadIdx.x, wave = tid >> 6, lane = tid & 63, quad = lane >> 4, l16 = lane & 15;
  int t0 = mt * 64;
  int hc = h * 64;
  size_t rowbase = (size_t)b * T;
  __shared__ __align__(16) bf16 vt[64 * 72];        // V tile transposed [hd][key]
  __shared__ __align__(16) bf16 sm[4][16 * 72];     // per-wave S tile [row][key]

  bf16x8 qf[2];
  {
    const bf16* qp = Qb + (rowbase + t0 + wave * 16 + l16) * D + hc + quad * 8;
    qf[0] = *reinterpret_cast<const bf16x8*>(qp);
    qf[1] = *reinterpret_cast<const bf16x8*>(qp + 32);
  }
  f32x4 oacc[4] = {};
  float dsum[4] = {0.f, 0.f, 0.f, 0.f};
  int ntile = mt + 1;
  for (int kt = 0; kt < ntile; ++kt) {
    int s0 = kt * 64;
    __syncthreads();  // protect vt/sm from previous iteration's readers
    for (int i = 0; i < 16; ++i) {
      int e = i * 256 + tid; int key = e >> 6, hd = e & 63;
      vt[hd * 72 + key] = Vb[(rowbase + s0 + key) * D + hc + hd];
    }
    __syncthreads();
    // S = Q K^T
    f32x4 sacc[4] = {};
    #pragma unroll
    for (int kk = 0; kk < 2; ++kk) {
      #pragma unroll
      for (int nt = 0; nt < 4; ++nt) {
        const bf16* kp = Kb + (rowbase + s0 + nt * 16 + l16) * D + hc + kk * 32 + quad * 8;
        bf16x8 bfr = *reinterpret_cast<const bf16x8*>(kp);
        sacc[nt] = __builtin_amdgcn_mfma_f32_16x16x32_bf16(qf[kk], bfr, sacc[nt], 0, 0, 0);
      }
    }
    // scale, causal, silu, clamp; accumulate denom; park S in LDS
    int trow = t0 + wave * 16 + quad * 4;
    #pragma unroll
    for (int nt = 0; nt < 4; ++nt) {
      #pragma unroll
      for (int r = 0; r < 4; ++r) {
        int sc = s0 + nt * 16 + l16;
        float v = sacc[nt][r] * 0.125f;
        float a = (sc <= trow + r && v > 0.f) ? v / (1.f + __expf(-v)) : 0.f;
        bf16 ab = __float2bfloat16(a);
        dsum[r] += __bfloat162float(ab);
        sm[wave][(quad * 4 + r) * 72 + nt * 16 + l16] = ab;
      }
    }
    __syncthreads();  // make sm writes visible (also orders vs any reordering)
    // O += S @ V
    #pragma unroll
    for (int kk = 0; kk < 2; ++kk) {
      bf16x8 af = *reinterpret_cast<const bf16x8*>(&sm[wave][l16 * 72 + kk * 32 + quad * 8]);
      #pragma unroll
      for (int nt = 0; nt < 4; ++nt) {
        bf16x8 bfr = *reinterpret_cast<const bf16x8*>(&vt[(nt * 16 + l16) * 72 + kk * 32 + quad * 8]);
        oacc[nt] = __builtin_amdgcn_mfma_f32_16x16x32_bf16(af, bfr, oacc[nt], 0, 0, 0);
      }
    }
  }
  #pragma unroll
  for (int r = 0; r < 4; ++r) {
    #pragma unroll
    for (int off = 1; off < 16; off <<= 1) dsum[r] += __shfl_xor(dsum[r], off);
  }
  int trow = t0 + wave * 16 + quad * 4;
  #pragma unroll
  for (int nt = 0; nt < 4; ++nt) {
    int col = hc + nt * 16 + l16;
    #pragma unroll
    for (int r = 0; r < 4; ++r) {
      float dnm = dsum[r];
      float o = (dnm > 1e-12f) ? oacc[nt][r] / (dnm + 1e-8f) : 0.f;
      AV[(rowbase + trow + r) * D + col] = o;
    }
  }
}

// ---------------- launch ----------------
extern "C" void kernel_launch(void* const* d_in, const int* in_sizes, int n_in,
                              void* d_out, int out_size, void* d_ws, size_t ws_size,
                              hipStream_t stream) {
  const int* seqs = (const int*)d_in[0];
  // d_in[1] attn_mask: deterministic causal tril -> hardcoded
  const void* item = d_in[2];
  const void* pos  = d_in[3];

  // canonical fp32 params in ws
  float* params = (float*)d_ws;
  int* flagp = (int*)((char*)d_ws + 24 * 1024);
  char* base = (char*)d_ws + 32 * 1024;
  const size_t MB = 1024 * 1024;
  float* x  = (float*)base;                 // 8 MB fp32 residual
  float* av = (float*)(base + 8 * MB);      // 8 MB fp32 attention out
  bf16* qn  = (bf16*)av;                    // alias: qn dead before flash writes av
  bf16* b1  = (bf16*)(base + 16 * MB);      // U        (later: ln2-out)
  bf16* b2  = (bf16*)(base + 20 * MB);      // V        (later: gelu hidden)
  bf16* b3  = (bf16*)(base + 24 * MB);      // Q        (later: tb)
  bf16* b4  = (bf16*)(base + 28 * MB);      // K
  bf16* wT  = (bf16*)(base + 32 * MB);      // 28 * 16384 bf16 = 896 KB

  // canonical param offsets
  float* p_emb  = params + 0;
  float* p_ln1  = params + 128;
  float* p_hstu = params + 640;
  float* p_ln2  = params + 1152;
  float* p_last = params + 1664;
  float* p_Ub   = params + 1792;
  float* p_Vb   = params + 2304;
  float* p_Qb   = params + 2816;
  float* p_Kb   = params + 3328;
  float* p_f2b  = params + 3840;
  float* p_c1b  = params + 4352;
  float* p_c2b  = params + 4864;

  PPtrs pp;
  pp.p[0] = d_in[4];  pp.p[1] = d_in[5];  pp.p[2] = d_in[16]; pp.p[3] = d_in[17];
  pp.p[4] = d_in[22]; pp.p[5] = d_in[7];  pp.p[6] = d_in[9];  pp.p[7] = d_in[11];
  pp.p[8] = d_in[13]; pp.p[9] = d_in[15]; pp.p[10] = d_in[19]; pp.p[11] = d_in[21];
  detect_convert_k<<<1, 256, 0, stream>>>(item, pp, params, flagp);

  WPtrs wp;
  wp.p[0] = d_in[6]; wp.p[1] = d_in[8]; wp.p[2] = d_in[10]; wp.p[3] = d_in[12];
  wp.p[4] = d_in[14]; wp.p[5] = d_in[18]; wp.p[6] = d_in[20];
  transpose_w_k<<<dim3(4, 7), 256, 0, stream>>>(wp, wT, flagp);
  embed_rms_k<<<M / 4, 256, 0, stream>>>(seqs, item, pos, p_emb, x, flagp);

  dim3 ggrid(M / 64, 2);
  for (int l = 0; l < 4; ++l) {
    rms_k<<<M / 4, 256, 0, stream>>>(x, p_ln1 + l * D, nullptr, qn);
    gemm_k<<<ggrid, 256, 0, stream>>>(qn, wT + (size_t)(0 * 4 + l) * 16384, p_Ub + l * D, b1, nullptr, 0);
    gemm_k<<<ggrid, 256, 0, stream>>>(qn, wT + (size_t)(1 * 4 + l) * 16384, p_Vb + l * D, b2, nullptr, 0);
    gemm_k<<<ggrid, 256, 0, stream>>>(qn, wT + (size_t)(2 * 4 + l) * 16384, p_Qb + l * D, b3, nullptr, 0);
    gemm_k<<<ggrid, 256, 0, stream>>>(qn, wT + (size_t)(3 * 4 + l) * 16384, p_Kb + l * D, b4, nullptr, 0);
    flash_k<<<dim3(T / 64, 16), 256, 0, stream>>>(b3, b4, b2, av);
    rms_k<<<M / 4, 256, 0, stream>>>(av, p_hstu + l * D, b1, b3);
    gemm_k<<<ggrid, 256, 0, stream>>>(b3, wT + (size_t)(4 * 4 + l) * 16384, p_f2b + l * D, nullptr, x, 2);
    rms_k<<<M / 4, 256, 0, stream>>>(x, p_ln2 + l * D, nullptr, b1);
    gemm_k<<<ggrid, 256, 0, stream>>>(b1, wT + (size_t)(5 * 4 + l) * 16384, p_c1b + l * D, b2, nullptr, 1);
    gemm_k<<<ggrid, 256, 0, stream>>>(b2, wT + (size_t)(6 * 4 + l) * 16384, p_c2b + l * D, nullptr, x, 2);
  }
  rms_out_k<<<M / 4, 256, 0, stream>>>(x, p_last, d_out, flagp);
}

// Round 3
// 861.825 us; speedup vs baseline: 1.0160x; 1.0160x over previous
//
#include <hip/hip_runtime.h>
#include <hip/hip_bf16.h>

typedef __bf16 bf16x8 __attribute__((ext_vector_type(8)));
typedef float f32x4 __attribute__((ext_vector_type(4)));
using bf16 = __hip_bfloat16;

constexpr int T = 2048;
constexpr int D = 128;
constexpr int M = 8 * 2048;   // B*T rows
constexpr int LDA = 136;      // 128 + 8 bf16 pad

// flag-aware scalar load: input may be float32 or bf16, decided at runtime
__device__ inline float ldf(const void* p, size_t i, int isf32) {
  if (isf32) return ((const float*)p)[i];
  unsigned u = ((const unsigned short*)p)[i];
  return __uint_as_float(u << 16);
}

// ---------------- dtype probe + param conversion ----------------
struct PPtrs { const void* p[12]; };

__global__ void detect_convert_k(const void* __restrict__ item, PPtrs ps,
                                 float* __restrict__ params, int* __restrict__ flagp) {
  __shared__ int cnt[4];
  __shared__ int flagLDS;
  int tid = threadIdx.x;
  unsigned short lo = ((const unsigned short*)item)[tid * 2];
  float bv = __uint_as_float((unsigned)lo << 16);
  float a = fabsf(bv);
  bool okb = (a > 1e-5f) && (a < 0.5f);
  unsigned long long m = __ballot(okb);
  if ((tid & 63) == 0) cnt[tid >> 6] = __popcll(m);
  __syncthreads();
  if (tid == 0) {
    int tot = cnt[0] + cnt[1] + cnt[2] + cnt[3];
    int f = (tot < 128) ? 1 : 0;  // 1 = inputs are float32
    flagLDS = f;
    *flagp = f;
  }
  __syncthreads();
  int f = flagLDS;
  const int lens[12] = {128, 512, 512, 512, 128, 512, 512, 512, 512, 512, 512, 512};
  int off = 0;
  for (int j = 0; j < 12; ++j) {
    for (int i = tid; i < lens[j]; i += 256) params[off + i] = ldf(ps.p[j], i, f);
    off += lens[j];
  }
}

// ---------------- weight transpose: W[K][N] -> WT[N][K] (canonical bf16) ----------------
struct WPtrs { const void* p[7]; };

__global__ void transpose_w_k(WPtrs w, bf16* __restrict__ dst, const int* __restrict__ flagp) {
  int f = *flagp;
  int l = blockIdx.x, wi = blockIdx.y;
  const void* s = w.p[wi];
  size_t sbase = (size_t)l * 16384;
  bf16* d = dst + ((size_t)wi * 4 + l) * 16384;
  for (int i = 0; i < 64; ++i) {
    int e = i * 256 + threadIdx.x;                       // e = n*128 + k
    d[e] = __float2bfloat16(ldf(s, sbase + (size_t)(e & 127) * 128 + (e >> 7), f));
  }
}

// ---------------- embedding gather + RMSNorm -> x fp32 ----------------
__global__ void embed_rms_k(const int* __restrict__ seqs, const void* __restrict__ item,
                            const void* __restrict__ pos, const float* __restrict__ scale,
                            float* __restrict__ x, const int* __restrict__ flagp) {
  int f = *flagp;
  int row = blockIdx.x * 4 + (threadIdx.x >> 6);
  int lane = threadIdx.x & 63;
  int t = row & (T - 1);
  int idx = seqs[row];
  int c = lane * 2;
  float e0 = ldf(item, (size_t)idx * D + c, f)     + ldf(pos, (size_t)(t + 1) * D + c, f);
  float e1 = ldf(item, (size_t)idx * D + c + 1, f) + ldf(pos, (size_t)(t + 1) * D + c + 1, f);
  float ss = e0 * e0 + e1 * e1;
  #pragma unroll
  for (int off = 32; off; off >>= 1) ss += __shfl_xor(ss, off);
  float rs = rsqrtf(ss * (1.f / 128.f) + 1e-8f);
  float* xr = x + (size_t)row * D + c;
  xr[0] = e0 * rs * scale[c];
  xr[1] = e1 * rs * scale[c + 1];
}

// ---------------- final RMSNorm -> d_out (dtype per flag) ----------------
__global__ void rms_out_k(const float* __restrict__ x, const float* __restrict__ scale,
                          void* __restrict__ out, const int* __restrict__ flagp) {
  int row = blockIdx.x * 4 + (threadIdx.x >> 6);
  int lane = threadIdx.x & 63;
  int c = lane * 2;
  float2 v = *reinterpret_cast<const float2*>(x + (size_t)row * D + c);
  float ss = v.x * v.x + v.y * v.y;
  #pragma unroll
  for (int off = 32; off; off >>= 1) ss += __shfl_xor(ss, off);
  float rs = rsqrtf(ss * (1.f / 128.f) + 1e-8f);
  float o0 = v.x * rs * scale[c];
  float o1 = v.y * rs * scale[c + 1];
  if (*flagp) {
    float2 ov; ov.x = o0; ov.y = o1;
    *reinterpret_cast<float2*>((float*)out + (size_t)row * D + c) = ov;
  } else {
    __hip_bfloat162 ov;
    ov.x = __float2bfloat16(o0); ov.y = __float2bfloat16(o1);
    *reinterpret_cast<__hip_bfloat162*>((bf16*)out + (size_t)row * D + c) = ov;
  }
}

// ---------------- GEMM: 128x64 tile, optional fused RMSNorm on A ----------------
// a_src: 0 = A bf16 plain; 1 = A fp32 + rms(scale); 2 = A fp32 + rms(scale) * mulU
// mode:  0 = silu -> bf16 out[wsel]; 1 = gelu -> bf16 out[0]; 2 = resid fp32 +=
struct GArgs {
  const void* A;
  const float* rms_scale;
  const bf16* mulU;
  const bf16* Wbase; int wstride;      // elements; fused QKVU: 65536, single: 0
  const float* biasb;                   // biasb[wsel*512 + ncl]
  bf16* o0; bf16* o1; bf16* o2; bf16* o3;
  float* resid;
  int a_src; int mode;
};

__global__ __launch_bounds__(256) void gemm_k(GArgs g) {
  __shared__ __align__(16) bf16 la[128 * LDA];
  __shared__ __align__(16) bf16 lb[64 * LDA];
  int tid = threadIdx.x;
  int m0 = blockIdx.x * 128;
  int ng0 = blockIdx.y * 64;
  int wsel = ng0 >> 7, nc0 = ng0 & 127;
  const bf16* wp = g.Wbase + (size_t)wsel * g.wstride;
  #pragma unroll
  for (int i = 0; i < 4; ++i) {
    int ch = i * 256 + tid, r = ch >> 4, c = ch & 15;
    *reinterpret_cast<uint4*>(&lb[r * LDA + c * 8]) =
        *reinterpret_cast<const uint4*>(wp + (size_t)(nc0 + r) * 128 + c * 8);
  }
  if (g.a_src == 0) {
    const bf16* A = (const bf16*)g.A;
    #pragma unroll
    for (int i = 0; i < 8; ++i) {
      int ch = i * 256 + tid, r = ch >> 4, c = ch & 15;
      *reinterpret_cast<uint4*>(&la[r * LDA + c * 8]) =
          *reinterpret_cast<const uint4*>(A + (size_t)(m0 + r) * 128 + c * 8);
    }
  } else {
    const float* X = (const float*)g.A;
    int r = tid >> 1, h = tid & 1;
    const float* xr = X + (size_t)(m0 + r) * 128 + h * 64;
    float s = 0.f;
    #pragma unroll
    for (int j = 0; j < 16; ++j) {
      float4 v = reinterpret_cast<const float4*>(xr)[j];
      s += v.x * v.x + v.y * v.y + v.z * v.z + v.w * v.w;
    }
    s += __shfl_xor(s, 1);
    float rs = rsqrtf(s * (1.f / 128.f) + 1e-8f);
    #pragma unroll
    for (int j = 0; j < 8; ++j) {
      float4 v0 = reinterpret_cast<const float4*>(xr)[2 * j];
      float4 v1 = reinterpret_cast<const float4*>(xr)[2 * j + 1];
      int c0 = h * 64 + j * 8;
      float4 s0 = reinterpret_cast<const float4*>(g.rms_scale + c0)[0];
      float4 s1 = reinterpret_cast<const float4*>(g.rms_scale + c0)[1];
      float f[8] = {v0.x * rs * s0.x, v0.y * rs * s0.y, v0.z * rs * s0.z, v0.w * rs * s0.w,
                    v1.x * rs * s1.x, v1.y * rs * s1.y, v1.z * rs * s1.z, v1.w * rs * s1.w};
      if (g.a_src == 2) {
        union { bf16x8 v; __hip_bfloat162 h2[4]; } uu;
        uu.v = *reinterpret_cast<const bf16x8*>(g.mulU + (size_t)(m0 + r) * 128 + c0);
        #pragma unroll
        for (int q = 0; q < 4; ++q) {
          f[2 * q]     *= __bfloat162float(uu.h2[q].x);
          f[2 * q + 1] *= __bfloat162float(uu.h2[q].y);
        }
      }
      union { bf16x8 v; __hip_bfloat16 hh[8]; } ou;
      #pragma unroll
      for (int q = 0; q < 8; ++q) ou.hh[q] = __float2bfloat16(f[q]);
      *reinterpret_cast<bf16x8*>(&la[r * LDA + c0]) = ou.v;
    }
  }
  __syncthreads();
  int wv = tid >> 6, lane = tid & 63, quad = lane >> 4, l16 = lane & 15;
  f32x4 acc[2][4] = {};
  #pragma unroll
  for (int kk = 0; kk < 4; ++kk) {
    bf16x8 a0 = *reinterpret_cast<const bf16x8*>(&la[(wv * 32 + l16) * LDA + kk * 32 + quad * 8]);
    bf16x8 a1 = *reinterpret_cast<const bf16x8*>(&la[(wv * 32 + 16 + l16) * LDA + kk * 32 + quad * 8]);
    #pragma unroll
    for (int nt = 0; nt < 4; ++nt) {
      bf16x8 b = *reinterpret_cast<const bf16x8*>(&lb[(nt * 16 + l16) * LDA + kk * 32 + quad * 8]);
      acc[0][nt] = __builtin_amdgcn_mfma_f32_16x16x32_bf16(a0, b, acc[0][nt], 0, 0, 0);
      acc[1][nt] = __builtin_amdgcn_mfma_f32_16x16x32_bf16(a1, b, acc[1][nt], 0, 0, 0);
    }
  }
  bf16* outs[4] = {g.o0, g.o1, g.o2, g.o3};
  bf16* out = outs[wsel];
  #pragma unroll
  for (int mi = 0; mi < 2; ++mi) {
    int rbase = m0 + wv * 32 + mi * 16 + quad * 4;
    #pragma unroll
    for (int nt = 0; nt < 4; ++nt) {
      int ncl = nc0 + nt * 16 + l16;
      float bv = g.biasb[wsel * 512 + ncl];
      #pragma unroll
      for (int r = 0; r < 4; ++r) {
        float v = acc[mi][nt][r] + bv;
        size_t off = (size_t)(rbase + r) * 128 + ncl;
        if (g.mode == 0) {
          v = v / (1.f + __expf(-v));
          out[off] = __float2bfloat16(v);
        } else if (g.mode == 1) {
          v = 0.5f * v * (1.f + erff(v * 0.70710678118f));
          out[off] = __float2bfloat16(v);
        } else {
          g.resid[off] += v;
        }
      }
    }
  }
}

// ---------------- HSTU flash attention, 8 waves, kt parity-split ----------------
// wave = p*4 + rg: parity p handles kt ≡ p (mod 2); rg owns Q-rows t0+rg*16..+15.
__global__ __launch_bounds__(512) void flash_k(const bf16* __restrict__ Qb,
    const bf16* __restrict__ Kb, const bf16* __restrict__ Vb, float* __restrict__ AV) {
  int mt = blockIdx.x, bh = blockIdx.y;
  int b = bh >> 1, h = bh & 1;
  int tid = threadIdx.x, wave = tid >> 6, lane = tid & 63, quad = lane >> 4, l16 = lane & 15;
  int p = wave >> 2, rg = wave & 3;
  int t0 = mt * 64, hc = h * 64;
  size_t rowbase = (size_t)b * T;
  __shared__ __align__(16) char lds[36864 + 256];
  bf16* vt = (bf16*)lds + p * 4608;                 // [hd][key] 64x72, per parity
  bf16* sm = (bf16*)(lds + 18432) + wave * 1152;    // per-wave 16x72 S tile

  bf16x8 qf[2];
  {
    const bf16* qp = Qb + (rowbase + t0 + rg * 16 + l16) * D + hc + quad * 8;
    qf[0] = *reinterpret_cast<const bf16x8*>(qp);
    qf[1] = *reinterpret_cast<const bf16x8*>(qp + 32);
  }
  f32x4 oacc[4] = {};
  float dsum[4] = {0.f, 0.f, 0.f, 0.f};
  int ntile = mt + 1;
  int npair = (ntile + 1) >> 1;
  for (int k2 = 0; k2 < npair; ++k2) {
    int kt = k2 * 2 + p;
    bool act = kt < ntile;
    int s0 = kt * 64;
    __syncthreads();
    if (act) {
      int g = tid & 255;
      for (int i = 0; i < 16; ++i) {
        int e = i * 256 + g; int key = e >> 6, hd = e & 63;
        vt[hd * 72 + key] = Vb[(rowbase + s0 + key) * D + hc + hd];
      }
    }
    __syncthreads();
    if (act) {
      f32x4 sacc[4] = {};
      #pragma unroll
      for (int kk = 0; kk < 2; ++kk) {
        #pragma unroll
        for (int nt = 0; nt < 4; ++nt) {
          const bf16* kp = Kb + (rowbase + s0 + nt * 16 + l16) * D + hc + kk * 32 + quad * 8;
          bf16x8 bfr = *reinterpret_cast<const bf16x8*>(kp);
          sacc[nt] = __builtin_amdgcn_mfma_f32_16x16x32_bf16(qf[kk], bfr, sacc[nt], 0, 0, 0);
        }
      }
      int trow = t0 + rg * 16 + quad * 4;
      #pragma unroll
      for (int nt = 0; nt < 4; ++nt) {
        #pragma unroll
        for (int r = 0; r < 4; ++r) {
          int sc = s0 + nt * 16 + l16;
          float v = sacc[nt][r] * 0.125f;
          float a = (sc <= trow + r && v > 0.f) ? v / (1.f + __expf(-v)) : 0.f;
          bf16 ab = __float2bfloat16(a);
          dsum[r] += __bfloat162float(ab);
          sm[(quad * 4 + r) * 72 + nt * 16 + l16] = ab;
        }
      }
    }
    __syncthreads();
    if (act) {
      #pragma unroll
      for (int kk = 0; kk < 2; ++kk) {
        bf16x8 af = *reinterpret_cast<const bf16x8*>(&sm[l16 * 72 + kk * 32 + quad * 8]);
        #pragma unroll
        for (int nt = 0; nt < 4; ++nt) {
          bf16x8 bfr = *reinterpret_cast<const bf16x8*>(&vt[(nt * 16 + l16) * 72 + kk * 32 + quad * 8]);
          oacc[nt] = __builtin_amdgcn_mfma_f32_16x16x32_bf16(af, bfr, oacc[nt], 0, 0, 0);
        }
      }
    }
  }
  // reduce dsum across the 16 lanes of each quad group
  #pragma unroll
  for (int r = 0; r < 4; ++r) {
    #pragma unroll
    for (int off = 1; off < 16; off <<= 1) dsum[r] += __shfl_xor(dsum[r], off);
  }
  // cross-parity merge via LDS (overlay on vt area)
  __syncthreads();
  float* red = (float*)lds;          // 64 rows x 64 cols fp32
  float* redd = red + 4096;          // 64 row sums
  if (p == 1) {
    #pragma unroll
    for (int nt = 0; nt < 4; ++nt)
      #pragma unroll
      for (int r = 0; r < 4; ++r)
        red[(rg * 16 + quad * 4 + r) * 64 + nt * 16 + l16] = oacc[nt][r];
    if (l16 == 0) {
      #pragma unroll
      for (int r = 0; r < 4; ++r) redd[rg * 16 + quad * 4 + r] = dsum[r];
    }
  }
  __syncthreads();
  if (p == 0) {
    int trow = t0 + rg * 16 + quad * 4;
    #pragma unroll
    for (int r = 0; r < 4; ++r) dsum[r] += redd[rg * 16 + quad * 4 + r];
    #pragma unroll
    for (int nt = 0; nt < 4; ++nt) {
      int col = hc + nt * 16 + l16;
      #pragma unroll
      for (int r = 0; r < 4; ++r) {
        float o = oacc[nt][r] + red[(rg * 16 + quad * 4 + r) * 64 + nt * 16 + l16];
        float dnm = dsum[r];
        AV[(rowbase + trow + r) * D + col] = (dnm > 1e-12f) ? o / (dnm + 1e-8f) : 0.f;
      }
    }
  }
}

// ---------------- launch ----------------
extern "C" void kernel_launch(void* const* d_in, const int* in_sizes, int n_in,
                              void* d_out, int out_size, void* d_ws, size_t ws_size,
                              hipStream_t stream) {
  const int* seqs = (const int*)d_in[0];
  const void* item = d_in[2];
  const void* pos  = d_in[3];

  float* params = (float*)d_ws;
  int* flagp = (int*)((char*)d_ws + 24 * 1024);
  char* base = (char*)d_ws + 32 * 1024;
  const size_t MB = 1024 * 1024;
  float* x  = (float*)base;                 // 8 MB fp32 residual
  float* av = (float*)(base + 8 * MB);      // 8 MB fp32 attention out
  bf16* b1  = (bf16*)(base + 16 * MB);      // U
  bf16* b2  = (bf16*)(base + 20 * MB);      // V / gelu hidden
  bf16* b3  = (bf16*)(base + 24 * MB);      // Q
  bf16* b4  = (bf16*)(base + 28 * MB);      // K
  bf16* wT  = (bf16*)(base + 32 * MB);      // 28 * 16384 bf16

  float* p_emb  = params + 0;
  float* p_ln1  = params + 128;
  float* p_hstu = params + 640;
  float* p_ln2  = params + 1152;
  float* p_last = params + 1664;
  float* p_qkvu_b = params + 1792;          // Ub,Vb,Qb,Kb each 512 (L-major 128)
  float* p_f2b  = params + 3840;
  float* p_c1b  = params + 4352;
  float* p_c2b  = params + 4864;

  PPtrs pp;
  pp.p[0] = d_in[4];  pp.p[1] = d_in[5];  pp.p[2] = d_in[16]; pp.p[3] = d_in[17];
  pp.p[4] = d_in[22]; pp.p[5] = d_in[7];  pp.p[6] = d_in[9];  pp.p[7] = d_in[11];
  pp.p[8] = d_in[13]; pp.p[9] = d_in[15]; pp.p[10] = d_in[19]; pp.p[11] = d_in[21];
  detect_convert_k<<<1, 256, 0, stream>>>(item, pp, params, flagp);

  WPtrs wp;
  wp.p[0] = d_in[6]; wp.p[1] = d_in[8]; wp.p[2] = d_in[10]; wp.p[3] = d_in[12];
  wp.p[4] = d_in[14]; wp.p[5] = d_in[18]; wp.p[6] = d_in[20];
  transpose_w_k<<<dim3(4, 7), 256, 0, stream>>>(wp, wT, flagp);
  embed_rms_k<<<M / 4, 256, 0, stream>>>(seqs, item, pos, p_emb, x, flagp);

  for (int l = 0; l < 4; ++l) {
    GArgs g1 = { x, p_ln1 + l * 128, nullptr, wT + (size_t)l * 16384, 65536,
                 p_qkvu_b + l * 128, b1, b2, b3, b4, nullptr, 1, 0 };
    gemm_k<<<dim3(M / 128, 8), 256, 0, stream>>>(g1);
    flash_k<<<dim3(T / 64, 16), 512, 0, stream>>>(b3, b4, b2, av);
    GArgs g2 = { av, p_hstu + l * 128, b1, wT + (size_t)(16 + l) * 16384, 0,
                 p_f2b + l * 128, nullptr, nullptr, nullptr, nullptr, x, 2, 2 };
    gemm_k<<<dim3(M / 128, 2), 256, 0, stream>>>(g2);
    GArgs g3 = { x, p_ln2 + l * 128, nullptr, wT + (size_t)(20 + l) * 16384, 0,
                 p_c1b + l * 128, b2, nullptr, nullptr, nullptr, nullptr, 1, 1 };
    gemm_k<<<dim3(M / 128, 2), 256, 0, stream>>>(g3);
    GArgs g4 = { b2, nullptr, nullptr, wT + (size_t)(24 + l) * 16384, 0,
                 p_c2b + l * 128, nullptr, nullptr, nullptr, nullptr, x, 0, 2 };
    gemm_k<<<dim3(M / 128, 2), 256, 0, stream>>>(g4);
  }
  rms_out_k<<<M / 4, 256, 0, stream>>>(x, p_last, d_out, flagp);
}

// Round 4
// 813.227 us; speedup vs baseline: 1.0767x; 1.0598x over previous
//
#include <hip/hip_runtime.h>
#include <hip/hip_bf16.h>

typedef __bf16 bf16x8 __attribute__((ext_vector_type(8)));
typedef float f32x4 __attribute__((ext_vector_type(4)));
using bf16 = __hip_bfloat16;

constexpr int T = 2048;
constexpr int M = 8 * 2048;   // B*T rows
constexpr int LDA = 136;      // bf16 tile stride: +8 pad -> 2-way bank alias (free)
constexpr int LDX = 132;      // fp32 tile stride: +4 pad

__device__ inline float ldf(const void* p, size_t i, int isf32) {
  if (isf32) return ((const float*)p)[i];
  unsigned u = ((const unsigned short*)p)[i];
  return __uint_as_float(u << 16);
}
__device__ inline float bf2f(unsigned short u) { return __uint_as_float((unsigned)u << 16); }
__device__ inline unsigned short bfb(float x) {
  __hip_bfloat16 h = __float2bfloat16(x);
  return *reinterpret_cast<unsigned short*>(&h);
}
__device__ inline float4 ld4(const void* p, size_t base, int c, int f) {
  if (f) return *(const float4*)((const float*)p + base + c);
  ushort4 u = *(const ushort4*)((const unsigned short*)p + base + c);
  float4 r; r.x = bf2f(u.x); r.y = bf2f(u.y); r.z = bf2f(u.z); r.w = bf2f(u.w);
  return r;
}
union BH4 { ushort4 u; unsigned short s[4]; };

// ---------------- dtype probe + param conversion ----------------
struct PPtrs { const void* p[12]; };

__global__ void detect_convert_k(const void* __restrict__ item, PPtrs ps,
                                 float* __restrict__ params, int* __restrict__ flagp) {
  __shared__ int cnt[4];
  __shared__ int flagLDS;
  int tid = threadIdx.x;
  unsigned short lo = ((const unsigned short*)item)[tid * 2];
  float a = fabsf(bf2f(lo));
  bool okb = (a > 1e-5f) && (a < 0.5f);
  unsigned long long m = __ballot(okb);
  if ((tid & 63) == 0) cnt[tid >> 6] = __popcll(m);
  __syncthreads();
  if (tid == 0) {
    int tot = cnt[0] + cnt[1] + cnt[2] + cnt[3];
    int f = (tot < 128) ? 1 : 0;  // 1 = inputs are float32
    flagLDS = f; *flagp = f;
  }
  __syncthreads();
  int f = flagLDS;
  const int lens[12] = {128, 512, 512, 512, 128, 512, 512, 512, 512, 512, 512, 512};
  int off = 0;
  for (int j = 0; j < 12; ++j) {
    for (int i = tid; i < lens[j]; i += 256) params[off + i] = ldf(ps.p[j], i, f);
    off += lens[j];
  }
}

// ---------------- weight transpose: W[K][N] -> WT[N][K] ----------------
struct WPtrs { const void* p[7]; };

__global__ void transpose_w_k(WPtrs w, bf16* __restrict__ dst, const int* __restrict__ flagp) {
  int f = *flagp;
  int l = blockIdx.x, wi = blockIdx.y;
  const void* s = w.p[wi];
  size_t sbase = (size_t)l * 16384;
  bf16* d = dst + ((size_t)wi * 4 + l) * 16384;
  for (int i = 0; i < 64; ++i) {
    int e = i * 256 + threadIdx.x;                       // e = n*128 + k
    d[e] = __float2bfloat16(ldf(s, sbase + (size_t)(e & 127) * 128 + (e >> 7), f));
  }
}

// ---------------- fused stage helpers ----------------
__device__ inline void wload(const bf16* w, uint4* wr, int tid) {
  #pragma unroll
  for (int i = 0; i < 8; ++i) wr[i] = ((const uint4*)w)[i * 256 + tid];
}
__device__ inline void wstore(bf16* lw, const uint4* wr, int tid) {
  #pragma unroll
  for (int i = 0; i < 8; ++i) {
    int ch = i * 256 + tid, r = ch >> 4, c = ch & 15;
    *(uint4*)&lw[r * LDA + c * 8] = wr[i];
  }
}
__device__ inline void stage_mfma(const bf16* la, const bf16* lw, f32x4* acc,
                                  int wv, int quad, int l16) {
  #pragma unroll
  for (int kk = 0; kk < 4; ++kk) {
    bf16x8 a = *(const bf16x8*)&la[(wv * 16 + l16) * LDA + kk * 32 + quad * 8];
    #pragma unroll
    for (int nt = 0; nt < 8; ++nt) {
      bf16x8 b = *(const bf16x8*)&lw[(nt * 16 + l16) * LDA + kk * 32 + quad * 8];
      acc[nt] = __builtin_amdgcn_mfma_f32_16x16x32_bf16(a, b, acc[nt], 0, 0, 0);
    }
  }
}
__device__ inline void zero8(f32x4* acc) {
  #pragma unroll
  for (int i = 0; i < 8; ++i) acc[i] = (f32x4){0.f, 0.f, 0.f, 0.f};
}
__device__ inline void epi_silu_rm(const f32x4* acc, const float* bias, bf16* outg,
                                   int m0, int wv, int quad, int l16) {
  #pragma unroll
  for (int nt = 0; nt < 8; ++nt) {
    int col = nt * 16 + l16; float bv = bias[col];
    #pragma unroll
    for (int r = 0; r < 4; ++r) {
      float v = acc[nt][r] + bv; v = v / (1.f + __expf(-v));
      outg[(size_t)(m0 + wv * 16 + quad * 4 + r) * 128 + col] = __float2bfloat16(v);
    }
  }
}
__device__ inline void epi_silu_vt(const f32x4* acc, const float* bias, bf16* vtg,
                                   int m0, int wv, int quad, int l16) {
  #pragma unroll
  for (int nt = 0; nt < 8; ++nt) {
    int col = nt * 16 + l16; float bv = bias[col];
    int h = col >> 6, hd = col & 63;
    #pragma unroll
    for (int r = 0; r < 4; ++r) {
      int gr = m0 + wv * 16 + quad * 4 + r;
      int b = gr >> 11, t = gr & 2047;
      float v = acc[nt][r] + bv; v = v / (1.f + __expf(-v));
      vtg[((size_t)(b * 2 + h) * 64 + hd) * 2048 + t] = __float2bfloat16(v);
    }
  }
}
__device__ inline void epi_resid(const f32x4* acc, const float* bias, float* lx,
                                 int wv, int quad, int l16) {
  #pragma unroll
  for (int nt = 0; nt < 8; ++nt) {
    int col = nt * 16 + l16; float bv = bias[col];
    #pragma unroll
    for (int r = 0; r < 4; ++r)
      lx[(wv * 16 + quad * 4 + r) * LDX + col] += acc[nt][r] + bv;
  }
}
__device__ inline void epi_gelu_la(const f32x4* acc, const float* bias, bf16* la,
                                   int wv, int quad, int l16) {
  #pragma unroll
  for (int nt = 0; nt < 8; ++nt) {
    int col = nt * 16 + l16; float bv = bias[col];
    #pragma unroll
    for (int r = 0; r < 4; ++r) {
      float v = acc[nt][r] + bv;
      v = 0.5f * v * (1.f + erff(v * 0.70710678118f));
      la[(wv * 16 + quad * 4 + r) * LDA + col] = __float2bfloat16(v);
    }
  }
}
// la[r][c] = rms(lx row)*scale[c]
__device__ inline void buildA_lx(const float* lx, const float* scale, bf16* la, int tid) {
  int r = tid >> 2, part = tid & 3;
  const float* xr = lx + r * LDX;
  float4 v[8]; float ss = 0.f;
  #pragma unroll
  for (int jj = 0; jj < 8; ++jj) {
    v[jj] = *(const float4*)&xr[part * 4 + jj * 16];
    ss += v[jj].x * v[jj].x + v[jj].y * v[jj].y + v[jj].z * v[jj].z + v[jj].w * v[jj].w;
  }
  ss += __shfl_xor(ss, 1); ss += __shfl_xor(ss, 2);
  float rs = rsqrtf(ss * (1.f / 128.f) + 1e-8f);
  #pragma unroll
  for (int jj = 0; jj < 8; ++jj) {
    int c = part * 4 + jj * 16;
    float4 s4 = *(const float4*)&scale[c];
    BH4 o;
    o.s[0] = bfb(v[jj].x * rs * s4.x); o.s[1] = bfb(v[jj].y * rs * s4.y);
    o.s[2] = bfb(v[jj].z * rs * s4.z); o.s[3] = bfb(v[jj].w * rs * s4.w);
    *(ushort4*)&la[r * LDA + c] = o.u;
  }
}
// la[r][c] = rms(av row)*hstu_s[c]*U[r][c]
__device__ inline void buildA0(const float* avg, const bf16* Ug, const float* hs,
                               bf16* la, int m0, int tid) {
  int r = tid >> 2, part = tid & 3;
  const float* ar = avg + (size_t)(m0 + r) * 128;
  const unsigned short* ur = (const unsigned short*)Ug + (size_t)(m0 + r) * 128;
  float4 v[8]; float ss = 0.f;
  #pragma unroll
  for (int jj = 0; jj < 8; ++jj) {
    v[jj] = *(const float4*)&ar[part * 4 + jj * 16];
    ss += v[jj].x * v[jj].x + v[jj].y * v[jj].y + v[jj].z * v[jj].z + v[jj].w * v[jj].w;
  }
  ss += __shfl_xor(ss, 1); ss += __shfl_xor(ss, 2);
  float rs = rsqrtf(ss * (1.f / 128.f) + 1e-8f);
  #pragma unroll
  for (int jj = 0; jj < 8; ++jj) {
    int c = part * 4 + jj * 16;
    float4 s4 = *(const float4*)&hs[c];
    ushort4 uu = *(const ushort4*)&ur[c];
    BH4 o;
    o.s[0] = bfb(v[jj].x * rs * s4.x * bf2f(uu.x));
    o.s[1] = bfb(v[jj].y * rs * s4.y * bf2f(uu.y));
    o.s[2] = bfb(v[jj].z * rs * s4.z * bf2f(uu.z));
    o.s[3] = bfb(v[jj].w * rs * s4.w * bf2f(uu.w));
    *(ushort4*)&la[r * LDA + c] = o.u;
  }
}
__device__ inline void final_out(const float* lx, const float* scale, void* dout,
                                 int m0, int tid, int f) {
  int r = tid >> 2, part = tid & 3;
  const float* xr = lx + r * LDX;
  float4 v[8]; float ss = 0.f;
  #pragma unroll
  for (int jj = 0; jj < 8; ++jj) {
    v[jj] = *(const float4*)&xr[part * 4 + jj * 16];
    ss += v[jj].x * v[jj].x + v[jj].y * v[jj].y + v[jj].z * v[jj].z + v[jj].w * v[jj].w;
  }
  ss += __shfl_xor(ss, 1); ss += __shfl_xor(ss, 2);
  float rs = rsqrtf(ss * (1.f / 128.f) + 1e-8f);
  #pragma unroll
  for (int jj = 0; jj < 8; ++jj) {
    int c = part * 4 + jj * 16;
    float4 s4 = *(const float4*)&scale[c];
    float o0 = v[jj].x * rs * s4.x, o1 = v[jj].y * rs * s4.y;
    float o2 = v[jj].z * rs * s4.z, o3 = v[jj].w * rs * s4.w;
    if (f) {
      float4 ov; ov.x = o0; ov.y = o1; ov.z = o2; ov.w = o3;
      *(float4*)((float*)dout + (size_t)(m0 + r) * 128 + c) = ov;
    } else {
      BH4 o; o.s[0] = bfb(o0); o.s[1] = bfb(o1); o.s[2] = bfb(o2); o.s[3] = bfb(o3);
      *(ushort4*)((unsigned short*)dout + (size_t)(m0 + r) * 128 + c) = o.u;
    }
  }
}

// QKVU stages for layer lnext: assumes la holds q = rms(x)*ln1
__device__ inline void qkvu_tail(bf16* la, bf16* lw, const bf16* wT, const float* params,
                                 int lnext, bf16* Ug, bf16* Qg, bf16* Kg, bf16* VTg,
                                 int m0, int tid) {
  int wv = tid >> 6, lane = tid & 63, quad = lane >> 4, l16 = lane & 15;
  const float* pb = params + 1792;
  uint4 wr[8]; f32x4 acc[8];
  // U
  wload(wT + (size_t)(0 * 4 + lnext) * 16384, wr, tid);
  wstore(lw, wr, tid); __syncthreads();
  zero8(acc); stage_mfma(la, lw, acc, wv, quad, l16); __syncthreads();
  // V (+U epi)
  wload(wT + (size_t)(1 * 4 + lnext) * 16384, wr, tid);
  epi_silu_rm(acc, pb + 0 * 512 + lnext * 128, Ug, m0, wv, quad, l16);
  wstore(lw, wr, tid); __syncthreads();
  zero8(acc); stage_mfma(la, lw, acc, wv, quad, l16); __syncthreads();
  // Q (+V epi -> VT scatter)
  wload(wT + (size_t)(2 * 4 + lnext) * 16384, wr, tid);
  epi_silu_vt(acc, pb + 1 * 512 + lnext * 128, VTg, m0, wv, quad, l16);
  wstore(lw, wr, tid); __syncthreads();
  zero8(acc); stage_mfma(la, lw, acc, wv, quad, l16); __syncthreads();
  // K (+Q epi)
  wload(wT + (size_t)(3 * 4 + lnext) * 16384, wr, tid);
  epi_silu_rm(acc, pb + 2 * 512 + lnext * 128, Qg, m0, wv, quad, l16);
  wstore(lw, wr, tid); __syncthreads();
  zero8(acc); stage_mfma(la, lw, acc, wv, quad, l16); __syncthreads();
  epi_silu_rm(acc, pb + 3 * 512 + lnext * 128, Kg, m0, wv, quad, l16);
}

// ---------------- pre: embed + rms + rms*ln1 + QKVU(0) ----------------
__global__ __launch_bounds__(256) void pre_k(const int* __restrict__ seqs,
    const void* __restrict__ item, const void* __restrict__ pos, const bf16* __restrict__ wT,
    const float* __restrict__ params, float* __restrict__ xg, bf16* __restrict__ Ug,
    bf16* __restrict__ Qg, bf16* __restrict__ Kg, bf16* __restrict__ VTg,
    const int* __restrict__ flagp) {
  __shared__ __align__(16) bf16 la[64 * LDA];
  __shared__ __align__(16) bf16 lw[128 * LDA];
  int f = *flagp;
  int tid = threadIdx.x, m0 = blockIdx.x * 64;
  {
    int r = tid >> 2, part = tid & 3;
    int gr = m0 + r, t = gr & 2047;
    int idx = seqs[gr];
    size_t ib = (size_t)idx * 128, pb = (size_t)(t + 1) * 128;
    float e[32]; float ss = 0.f;
    #pragma unroll
    for (int jj = 0; jj < 8; ++jj) {
      int c = part * 4 + jj * 16;
      float4 a = ld4(item, ib, c, f), b = ld4(pos, pb, c, f);
      e[jj * 4 + 0] = a.x + b.x; e[jj * 4 + 1] = a.y + b.y;
      e[jj * 4 + 2] = a.z + b.z; e[jj * 4 + 3] = a.w + b.w;
      #pragma unroll
      for (int q = 0; q < 4; ++q) ss += e[jj * 4 + q] * e[jj * 4 + q];
    }
    ss += __shfl_xor(ss, 1); ss += __shfl_xor(ss, 2);
    float rs = rsqrtf(ss * (1.f / 128.f) + 1e-8f);
    const float* es = params;
    float ss2 = 0.f;
    #pragma unroll
    for (int jj = 0; jj < 8; ++jj) {
      int c = part * 4 + jj * 16;
      #pragma unroll
      for (int q = 0; q < 4; ++q) {
        e[jj * 4 + q] = e[jj * 4 + q] * rs * es[c + q];
        ss2 += e[jj * 4 + q] * e[jj * 4 + q];
      }
    }
    ss2 += __shfl_xor(ss2, 1); ss2 += __shfl_xor(ss2, 2);
    float rs2 = rsqrtf(ss2 * (1.f / 128.f) + 1e-8f);
    const float* l1 = params + 128;   // ln1 layer 0
    #pragma unroll
    for (int jj = 0; jj < 8; ++jj) {
      int c = part * 4 + jj * 16;
      float4 xo; xo.x = e[jj*4]; xo.y = e[jj*4+1]; xo.z = e[jj*4+2]; xo.w = e[jj*4+3];
      *(float4*)&xg[(size_t)gr * 128 + c] = xo;
      BH4 o;
      o.s[0] = bfb(e[jj*4+0] * rs2 * l1[c+0]); o.s[1] = bfb(e[jj*4+1] * rs2 * l1[c+1]);
      o.s[2] = bfb(e[jj*4+2] * rs2 * l1[c+2]); o.s[3] = bfb(e[jj*4+3] * rs2 * l1[c+3]);
      *(ushort4*)&la[r * LDA + c] = o.u;
    }
  }
  qkvu_tail(la, lw, wT, params, 0, Ug, Qg, Kg, VTg, m0, tid);
}

// ---------------- post: resid/FFN for layer l + QKVU(l+1) (or final out) ----------------
__global__ __launch_bounds__(256) void post_k(int l, float* __restrict__ xg,
    const float* __restrict__ avg, bf16* __restrict__ Ug, bf16* __restrict__ Qg,
    bf16* __restrict__ Kg, bf16* __restrict__ VTg, const bf16* __restrict__ wT,
    const float* __restrict__ params, void* __restrict__ dout, const int* __restrict__ flagp) {
  __shared__ float lx[64 * LDX];
  __shared__ __align__(16) bf16 la[64 * LDA];
  __shared__ __align__(16) bf16 lw[128 * LDA];
  int tid = threadIdx.x, m0 = blockIdx.x * 64;
  int wv = tid >> 6, lane = tid & 63, quad = lane >> 4, l16 = lane & 15;
  uint4 wr[8]; f32x4 acc[8];
  // preload x rows into lx
  #pragma unroll
  for (int i = 0; i < 8; ++i) {
    int e4 = i * 1024 + tid * 4;
    float4 v = *(const float4*)&xg[(size_t)m0 * 128 + e4];
    int r = e4 >> 7, c = e4 & 127;
    *(float4*)&lx[r * LDX + c] = v;
  }
  // S0: f2
  wload(wT + (size_t)(16 + l) * 16384, wr, tid);
  buildA0(avg, Ug, params + 640 + l * 128, la, m0, tid);
  wstore(lw, wr, tid); __syncthreads();
  zero8(acc); stage_mfma(la, lw, acc, wv, quad, l16); __syncthreads();
  // S1: c1
  wload(wT + (size_t)(20 + l) * 16384, wr, tid);
  epi_resid(acc, params + 3840 + l * 128, lx, wv, quad, l16);
  __syncthreads();
  buildA_lx(lx, params + 1152 + l * 128, la, tid);
  wstore(lw, wr, tid); __syncthreads();
  zero8(acc); stage_mfma(la, lw, acc, wv, quad, l16); __syncthreads();
  // S2: c2
  wload(wT + (size_t)(24 + l) * 16384, wr, tid);
  epi_gelu_la(acc, params + 4352 + l * 128, la, wv, quad, l16);
  wstore(lw, wr, tid); __syncthreads();
  zero8(acc); stage_mfma(la, lw, acc, wv, quad, l16); __syncthreads();
  // E2: x += c2-out
  epi_resid(acc, params + 4864 + l * 128, lx, wv, quad, l16);
  __syncthreads();
  if (l == 3) { final_out(lx, params + 1664, dout, m0, tid, *flagp); return; }
  // writeback x
  #pragma unroll
  for (int i = 0; i < 8; ++i) {
    int e4 = i * 1024 + tid * 4;
    int r = e4 >> 7, c = e4 & 127;
    *(float4*)&xg[(size_t)m0 * 128 + e4] = *(const float4*)&lx[r * LDX + c];
  }
  buildA_lx(lx, params + 128 + (l + 1) * 128, la, tid);
  qkvu_tail(la, lw, wT, params, l + 1, Ug, Qg, Kg, VTg, m0, tid);
}

// ---------------- HSTU flash: barrier-free waves, kt parity split ----------------
// grid (16, 16), block 512 = 8 waves. wave = p*4+j; j's q-tile = (j*16+bx)*32 rows.
__global__ __launch_bounds__(512) void flash_k(const bf16* __restrict__ Qg,
    const bf16* __restrict__ Kg, const bf16* __restrict__ VTg, float* __restrict__ avg) {
  __shared__ __align__(16) char lds[36864];
  int bx = blockIdx.x, bh = blockIdx.y;
  int b = bh >> 1, h = bh & 1;
  int tid = threadIdx.x, wave = tid >> 6, lane = tid & 63, quad = lane >> 4, l16 = lane & 15;
  int p = wave >> 2, j = wave & 3;
  int q32 = j * 16 + bx;
  int r0 = q32 * 32;
  bf16* sm = (bf16*)lds + wave * 2304;   // 32x72 bf16 per wave

  const bf16* qbase = Qg + ((size_t)b * 2048 + r0) * 128 + h * 64;
  bf16x8 qf[2][2];
  #pragma unroll
  for (int mi = 0; mi < 2; ++mi)
    #pragma unroll
    for (int kk = 0; kk < 2; ++kk)
      qf[mi][kk] = *(const bf16x8*)(qbase + (size_t)(mi * 16 + l16) * 128 + kk * 32 + quad * 8);

  f32x4 oacc[2][4] = {};
  float ds[2][4] = {};
  int ntile = q32 / 2 + 1;
  for (int kt = p; kt < ntile; kt += 2) {
    int s0 = kt * 64;
    f32x4 sacc[2][4] = {};
    const bf16* kbase = Kg + ((size_t)b * 2048 + s0) * 128 + h * 64;
    #pragma unroll
    for (int kk = 0; kk < 2; ++kk)
      #pragma unroll
      for (int nt = 0; nt < 4; ++nt) {
        bf16x8 bfr = *(const bf16x8*)(kbase + (size_t)(nt * 16 + l16) * 128 + kk * 32 + quad * 8);
        sacc[0][nt] = __builtin_amdgcn_mfma_f32_16x16x32_bf16(qf[0][kk], bfr, sacc[0][nt], 0, 0, 0);
        sacc[1][nt] = __builtin_amdgcn_mfma_f32_16x16x32_bf16(qf[1][kk], bfr, sacc[1][nt], 0, 0, 0);
      }
    #pragma unroll
    for (int mi = 0; mi < 2; ++mi) {
      int trow = r0 + mi * 16 + quad * 4;
      #pragma unroll
      for (int nt = 0; nt < 4; ++nt) {
        int sc = s0 + nt * 16 + l16;
        #pragma unroll
        for (int r = 0; r < 4; ++r) {
          float v = sacc[mi][nt][r] * 0.125f;
          float a = (sc <= trow + r && v > 0.f) ? v / (1.f + __expf(-v)) : 0.f;
          bf16 ab = __float2bfloat16(a);
          ds[mi][r] += __bfloat162float(ab);
          sm[(mi * 16 + quad * 4 + r) * 72 + nt * 16 + l16] = ab;
        }
      }
    }
    const bf16* vbase = VTg + (size_t)bh * 64 * 2048 + s0;
    #pragma unroll
    for (int kk = 0; kk < 2; ++kk) {
      bf16x8 af0 = *(const bf16x8*)&sm[l16 * 72 + kk * 32 + quad * 8];
      bf16x8 af1 = *(const bf16x8*)&sm[(16 + l16) * 72 + kk * 32 + quad * 8];
      #pragma unroll
      for (int nt = 0; nt < 4; ++nt) {
        bf16x8 bfr = *(const bf16x8*)(vbase + (size_t)(nt * 16 + l16) * 2048 + kk * 32 + quad * 8);
        oacc[0][nt] = __builtin_amdgcn_mfma_f32_16x16x32_bf16(af0, bfr, oacc[0][nt], 0, 0, 0);
        oacc[1][nt] = __builtin_amdgcn_mfma_f32_16x16x32_bf16(af1, bfr, oacc[1][nt], 0, 0, 0);
      }
    }
  }
  #pragma unroll
  for (int mi = 0; mi < 2; ++mi)
    #pragma unroll
    for (int r = 0; r < 4; ++r) {
      #pragma unroll
      for (int off = 1; off < 16; off <<= 1) ds[mi][r] += __shfl_xor(ds[mi][r], off);
    }
  __syncthreads();   // all waves done with their sm before overlay
  float* mg = (float*)lds;
  float* mo = mg + j * 2112;
  float* md = mo + 2048;
  if (p == 1) {
    #pragma unroll
    for (int mi = 0; mi < 2; ++mi)
      #pragma unroll
      for (int nt = 0; nt < 4; ++nt)
        #pragma unroll
        for (int r = 0; r < 4; ++r)
          mo[(mi * 16 + quad * 4 + r) * 64 + nt * 16 + l16] = oacc[mi][nt][r];
    if (l16 == 0) {
      #pragma unroll
      for (int mi = 0; mi < 2; ++mi)
        #pragma unroll
        for (int r = 0; r < 4; ++r) md[mi * 16 + quad * 4 + r] = ds[mi][r];
    }
  }
  __syncthreads();
  if (p == 0) {
    #pragma unroll
    for (int mi = 0; mi < 2; ++mi) {
      #pragma unroll
      for (int r = 0; r < 4; ++r) ds[mi][r] += md[mi * 16 + quad * 4 + r];
      #pragma unroll
      for (int nt = 0; nt < 4; ++nt) {
        int col = h * 64 + nt * 16 + l16;
        #pragma unroll
        for (int r = 0; r < 4; ++r) {
          int row = r0 + mi * 16 + quad * 4 + r;
          float o = oacc[mi][nt][r] + mo[(mi * 16 + quad * 4 + r) * 64 + nt * 16 + l16];
          float dn = ds[mi][r];
          avg[((size_t)b * 2048 + row) * 128 + col] = (dn > 1e-12f) ? o / (dn + 1e-8f) : 0.f;
        }
      }
    }
  }
}

// ---------------- launch ----------------
extern "C" void kernel_launch(void* const* d_in, const int* in_sizes, int n_in,
                              void* d_out, int out_size, void* d_ws, size_t ws_size,
                              hipStream_t stream) {
  const int* seqs = (const int*)d_in[0];
  const void* item = d_in[2];
  const void* pos  = d_in[3];

  float* params = (float*)d_ws;
  int* flagp = (int*)((char*)d_ws + 24 * 1024);
  char* base = (char*)d_ws + 32 * 1024;
  const size_t MB = 1024 * 1024;
  float* x   = (float*)base;                 // 8 MB fp32 residual
  float* av  = (float*)(base + 8 * MB);      // 8 MB fp32 attention out
  bf16* Ug   = (bf16*)(base + 16 * MB);      // 4 MB
  bf16* Qg   = (bf16*)(base + 20 * MB);      // 4 MB
  bf16* Kg   = (bf16*)(base + 24 * MB);      // 4 MB
  bf16* VTg  = (bf16*)(base + 28 * MB);      // 4 MB  [bh][hd][t]
  bf16* wT   = (bf16*)(base + 32 * MB);      // 28 * 16384 bf16 = 896 KB

  PPtrs pp;
  pp.p[0] = d_in[4];  pp.p[1] = d_in[5];  pp.p[2] = d_in[16]; pp.p[3] = d_in[17];
  pp.p[4] = d_in[22]; pp.p[5] = d_in[7];  pp.p[6] = d_in[9];  pp.p[7] = d_in[11];
  pp.p[8] = d_in[13]; pp.p[9] = d_in[15]; pp.p[10] = d_in[19]; pp.p[11] = d_in[21];
  detect_convert_k<<<1, 256, 0, stream>>>(item, pp, params, flagp);

  WPtrs wp;
  wp.p[0] = d_in[6]; wp.p[1] = d_in[8]; wp.p[2] = d_in[10]; wp.p[3] = d_in[12];
  wp.p[4] = d_in[14]; wp.p[5] = d_in[18]; wp.p[6] = d_in[20];
  transpose_w_k<<<dim3(4, 7), 256, 0, stream>>>(wp, wT, flagp);

  pre_k<<<M / 64, 256, 0, stream>>>(seqs, item, pos, wT, params, x, Ug, Qg, Kg, VTg, flagp);

  for (int l = 0; l < 4; ++l) {
    flash_k<<<dim3(16, 16), 512, 0, stream>>>(Qg, Kg, VTg, av);
    post_k<<<M / 64, 256, 0, stream>>>(l, x, av, Ug, Qg, Kg, VTg, wT, params, d_out, flagp);
  }
}

// Round 5
// 624.181 us; speedup vs baseline: 1.4029x; 1.3029x over previous
//
#include <hip/hip_runtime.h>
#include <hip/hip_bf16.h>

typedef __bf16 bf16x8 __attribute__((ext_vector_type(8)));
typedef float f32x4 __attribute__((ext_vector_type(4)));
using bf16 = __hip_bfloat16;

constexpr int T = 2048;
constexpr int M = 8 * 2048;   // B*T rows

__device__ inline float ldf(const void* p, size_t i, int isf32) {
  if (isf32) return ((const float*)p)[i];
  unsigned u = ((const unsigned short*)p)[i];
  return __uint_as_float(u << 16);
}
__device__ inline float bf2f(unsigned short u) { return __uint_as_float((unsigned)u << 16); }
__device__ inline unsigned short bfb(float x) {
  __hip_bfloat16 h = __float2bfloat16(x);
  return *reinterpret_cast<unsigned short*>(&h);
}

// ---------------- dtype probe + param conversion ----------------
struct PPtrs { const void* p[12]; };

__global__ void detect_convert_k(const void* __restrict__ item, PPtrs ps,
                                 float* __restrict__ params, int* __restrict__ flagp) {
  __shared__ int cnt[4];
  __shared__ int flagLDS;
  int tid = threadIdx.x;
  unsigned short lo = ((const unsigned short*)item)[tid * 2];
  float a = fabsf(bf2f(lo));
  bool okb = (a > 1e-5f) && (a < 0.5f);
  unsigned long long m = __ballot(okb);
  if ((tid & 63) == 0) cnt[tid >> 6] = __popcll(m);
  __syncthreads();
  if (tid == 0) {
    int tot = cnt[0] + cnt[1] + cnt[2] + cnt[3];
    int f = (tot < 128) ? 1 : 0;  // 1 = inputs are float32
    flagLDS = f; *flagp = f;
  }
  __syncthreads();
  int f = flagLDS;
  const int lens[12] = {128, 512, 512, 512, 128, 512, 512, 512, 512, 512, 512, 512};
  int off = 0;
  for (int j = 0; j < 12; ++j) {
    for (int i = tid; i < lens[j]; i += 256) params[off + i] = ldf(ps.p[j], i, f);
    off += lens[j];
  }
}

// ---------------- weight transpose: W[K][N] -> WT[N][K] ----------------
struct WPtrs { const void* p[7]; };

__global__ void transpose_w_k(WPtrs w, bf16* __restrict__ dst, const int* __restrict__ flagp) {
  int f = *flagp;
  int l = blockIdx.x, wi = blockIdx.y;
  const void* s = w.p[wi];
  size_t sbase = (size_t)l * 16384;
  bf16* d = dst + ((size_t)wi * 4 + l) * 16384;
  for (int i = 0; i < 64; ++i) {
    int e = i * 256 + threadIdx.x;                       // e = n*128 + k
    d[e] = __float2bfloat16(ldf(s, sbase + (size_t)(e & 127) * 128 + (e >> 7), f));
  }
}

// ---------------- shared GEMM-stage helpers (all wave-private, no barriers) ----------------
// W fragments straight from global (L2-hot): w[kk][nt] = WT[nt*16+l16][kk*32+quad*8 ..+7]
__device__ inline void issueW(const bf16* wt, bf16x8 (&w)[4][8], int quad, int l16) {
  #pragma unroll
  for (int kk = 0; kk < 4; ++kk)
    #pragma unroll
    for (int nt = 0; nt < 8; ++nt)
      w[kk][nt] = *(const bf16x8*)(wt + (size_t)(nt * 16 + l16) * 128 + kk * 32 + quad * 8);
}
__device__ inline void mfma_stage(const bf16x8 (&a)[4], const bf16x8 (&w)[4][8], f32x4 (&acc)[8]) {
  #pragma unroll
  for (int kk = 0; kk < 4; ++kk)
    #pragma unroll
    for (int nt = 0; nt < 8; ++nt)
      acc[nt] = __builtin_amdgcn_mfma_f32_16x16x32_bf16(a[kk], w[kk][nt], acc[nt], 0, 0, 0);
}
__device__ inline void zero8(f32x4 (&acc)[8]) {
  #pragma unroll
  for (int i = 0; i < 8; ++i) acc[i] = (f32x4){0.f, 0.f, 0.f, 0.f};
}
__device__ inline void readA(const bf16* aw, bf16x8 (&a)[4], int quad, int l16) {
  #pragma unroll
  for (int kk = 0; kk < 4; ++kk)
    a[kk] = *(const bf16x8*)&aw[l16 * 136 + kk * 32 + quad * 8];
}
// xr[nt][r] C-layout: row quad*4+r, col nt*16+l16. Builds A = rms(row)*scale into aw.
__device__ inline void buildA_rms(const float (&xr)[8][4], const float* scale, bf16* aw,
                                  int quad, int l16) {
  float s8[8];
  #pragma unroll
  for (int nt = 0; nt < 8; ++nt) s8[nt] = scale[nt * 16 + l16];
  #pragma unroll
  for (int r = 0; r < 4; ++r) {
    float ss = 0.f;
    #pragma unroll
    for (int nt = 0; nt < 8; ++nt) ss += xr[nt][r] * xr[nt][r];
    ss += __shfl_xor(ss, 1); ss += __shfl_xor(ss, 2);
    ss += __shfl_xor(ss, 4); ss += __shfl_xor(ss, 8);
    float rs = rsqrtf(ss * (1.f / 128.f) + 1e-8f);
    #pragma unroll
    for (int nt = 0; nt < 8; ++nt)
      aw[(quad * 4 + r) * 136 + nt * 16 + l16] = __float2bfloat16(xr[nt][r] * rs * s8[nt]);
  }
}
__device__ inline void epi_silu_store(const f32x4 (&acc)[8], const float* bias, bf16* outg,
                                      int row0, int quad, int l16, float mulf) {
  #pragma unroll
  for (int nt = 0; nt < 8; ++nt) {
    int col = nt * 16 + l16; float bv = bias[col];
    #pragma unroll
    for (int r = 0; r < 4; ++r) {
      float v = acc[nt][r] + bv;
      v = v / (1.f + __expf(-v)) * mulf;
      outg[(size_t)(row0 + quad * 4 + r) * 128 + col] = __float2bfloat16(v);
    }
  }
}
__device__ inline void epi_silu_vt(const f32x4 (&acc)[8], const float* bias, bf16* vtg,
                                   int row0, int quad, int l16) {
  #pragma unroll
  for (int nt = 0; nt < 8; ++nt) {
    int col = nt * 16 + l16; float bv = bias[col];
    int h = col >> 6, hd = col & 63;
    #pragma unroll
    for (int r = 0; r < 4; ++r) {
      int gr = row0 + quad * 4 + r; int b = gr >> 11, t = gr & 2047;
      float v = acc[nt][r] + bv; v = v / (1.f + __expf(-v));
      vtg[((size_t)(b * 2 + h) * 64 + hd) * 2048 + t] = __float2bfloat16(v);
    }
  }
}
__device__ inline void epi_addx(const f32x4 (&acc)[8], const float* bias, float (&xr)[8][4],
                                int l16) {
  #pragma unroll
  for (int nt = 0; nt < 8; ++nt) {
    float bv = bias[nt * 16 + l16];
    #pragma unroll
    for (int r = 0; r < 4; ++r) xr[nt][r] += acc[nt][r] + bv;
  }
}

// QKVU stages for layer lnext: A = rms(xr)*ln1 shared across the 4 weight matrices.
// Q is pre-scaled by 0.125 (exact in bf16) so flash skips the per-element logits scale.
__device__ inline void qkvu_stages(const float (&xr)[8][4], bf16* aw, const bf16* wT,
    const float* params, int lnext, bf16* Ug, bf16* Qg, bf16* Kg, bf16* VTg,
    int row0, int quad, int l16) {
  buildA_rms(xr, params + 128 + lnext * 128, aw, quad, l16);
  bf16x8 a[4]; readA(aw, a, quad, l16);
  bf16x8 w[4][8]; f32x4 acc[8];
  const float* pb = params + 1792;
  issueW(wT + (size_t)(0 * 4 + lnext) * 16384, w, quad, l16);      // U
  zero8(acc); mfma_stage(a, w, acc);
  issueW(wT + (size_t)(1 * 4 + lnext) * 16384, w, quad, l16);      // V
  epi_silu_store(acc, pb + 0 * 512 + lnext * 128, Ug, row0, quad, l16, 1.f);
  zero8(acc); mfma_stage(a, w, acc);
  issueW(wT + (size_t)(2 * 4 + lnext) * 16384, w, quad, l16);      // Q
  epi_silu_vt(acc, pb + 1 * 512 + lnext * 128, VTg, row0, quad, l16);
  zero8(acc); mfma_stage(a, w, acc);
  issueW(wT + (size_t)(3 * 4 + lnext) * 16384, w, quad, l16);      // K
  epi_silu_store(acc, pb + 2 * 512 + lnext * 128, Qg, row0, quad, l16, 0.125f);
  zero8(acc); mfma_stage(a, w, acc);
  epi_silu_store(acc, pb + 3 * 512 + lnext * 128, Kg, row0, quad, l16, 1.f);
}

// ---------------- pre: embed + rms + QKVU(0). Barrier-free, wave owns 16 rows ----------------
__global__ __launch_bounds__(256) void pre_k(const int* __restrict__ seqs,
    const void* __restrict__ item, const void* __restrict__ pos, const bf16* __restrict__ wT,
    const float* __restrict__ params, float* __restrict__ xg, bf16* __restrict__ Ug,
    bf16* __restrict__ Qg, bf16* __restrict__ Kg, bf16* __restrict__ VTg,
    const int* __restrict__ flagp) {
  __shared__ __align__(16) bf16 awAll[4][16 * 136 + 8];
  int f = *flagp;
  int tid = threadIdx.x, wv = tid >> 6, lane = tid & 63, quad = lane >> 4, l16 = lane & 15;
  bf16* aw = awAll[wv];
  int row0 = blockIdx.x * 64 + wv * 16;
  int idxs[4];
  #pragma unroll
  for (int r = 0; r < 4; ++r) idxs[r] = seqs[row0 + quad * 4 + r];
  float xr[8][4];
  #pragma unroll
  for (int nt = 0; nt < 8; ++nt) {
    int col = nt * 16 + l16;
    #pragma unroll
    for (int r = 0; r < 4; ++r) {
      int gr = row0 + quad * 4 + r; int t = gr & 2047;
      xr[nt][r] = ldf(item, (size_t)idxs[r] * 128 + col, f)
                + ldf(pos, (size_t)(t + 1) * 128 + col, f);
    }
  }
  {  // x = rms(e)*emb_s
    float s8[8];
    #pragma unroll
    for (int nt = 0; nt < 8; ++nt) s8[nt] = params[nt * 16 + l16];
    #pragma unroll
    for (int r = 0; r < 4; ++r) {
      float ss = 0.f;
      #pragma unroll
      for (int nt = 0; nt < 8; ++nt) ss += xr[nt][r] * xr[nt][r];
      ss += __shfl_xor(ss, 1); ss += __shfl_xor(ss, 2);
      ss += __shfl_xor(ss, 4); ss += __shfl_xor(ss, 8);
      float rs = rsqrtf(ss * (1.f / 128.f) + 1e-8f);
      #pragma unroll
      for (int nt = 0; nt < 8; ++nt) xr[nt][r] *= rs * s8[nt];
    }
  }
  #pragma unroll
  for (int nt = 0; nt < 8; ++nt)
    #pragma unroll
    for (int r = 0; r < 4; ++r)
      xg[(size_t)(row0 + quad * 4 + r) * 128 + nt * 16 + l16] = xr[nt][r];
  qkvu_stages(xr, aw, wT, params, 0, Ug, Qg, Kg, VTg, row0, quad, l16);
}

// ---------------- post: f2+FFN for layer l, then QKVU(l+1) or final out ----------------
__global__ __launch_bounds__(256) void post_k(int l, float* __restrict__ xg,
    const float* __restrict__ avg, bf16* __restrict__ Ug, bf16* __restrict__ Qg,
    bf16* __restrict__ Kg, bf16* __restrict__ VTg, const bf16* __restrict__ wT,
    const float* __restrict__ params, void* __restrict__ dout, const int* __restrict__ flagp) {
  __shared__ __align__(16) bf16 awAll[4][16 * 136 + 8];
  int tid = threadIdx.x, wv = tid >> 6, lane = tid & 63, quad = lane >> 4, l16 = lane & 15;
  bf16* aw = awAll[wv];
  int row0 = blockIdx.x * 64 + wv * 16;
  bf16x8 w[4][8]; f32x4 acc[8];
  issueW(wT + (size_t)(16 + l) * 16384, w, quad, l16);             // f2
  float xr[8][4], av[8][4], uu[8][4];
  #pragma unroll
  for (int nt = 0; nt < 8; ++nt) {
    int col = nt * 16 + l16;
    #pragma unroll
    for (int r = 0; r < 4; ++r) {
      size_t off = (size_t)(row0 + quad * 4 + r) * 128 + col;
      xr[nt][r] = xg[off];
      av[nt][r] = avg[off];
      uu[nt][r] = bf2f(((const unsigned short*)Ug)[off]);
    }
  }
  {  // A = rms(av)*hstu_s*U
    const float* hs = params + 640 + l * 128;
    float s8[8];
    #pragma unroll
    for (int nt = 0; nt < 8; ++nt) s8[nt] = hs[nt * 16 + l16];
    #pragma unroll
    for (int r = 0; r < 4; ++r) {
      float ss = 0.f;
      #pragma unroll
      for (int nt = 0; nt < 8; ++nt) ss += av[nt][r] * av[nt][r];
      ss += __shfl_xor(ss, 1); ss += __shfl_xor(ss, 2);
      ss += __shfl_xor(ss, 4); ss += __shfl_xor(ss, 8);
      float rs = rsqrtf(ss * (1.f / 128.f) + 1e-8f);
      #pragma unroll
      for (int nt = 0; nt < 8; ++nt)
        aw[(quad * 4 + r) * 136 + nt * 16 + l16] =
            __float2bfloat16(av[nt][r] * rs * s8[nt] * uu[nt][r]);
    }
  }
  bf16x8 a[4]; readA(aw, a, quad, l16);
  zero8(acc); mfma_stage(a, w, acc);
  issueW(wT + (size_t)(20 + l) * 16384, w, quad, l16);             // c1
  epi_addx(acc, params + 3840 + l * 128, xr, l16);                 // x += f2
  buildA_rms(xr, params + 1152 + l * 128, aw, quad, l16);          // ln2
  readA(aw, a, quad, l16);
  zero8(acc); mfma_stage(a, w, acc);
  issueW(wT + (size_t)(24 + l) * 16384, w, quad, l16);             // c2
  {  // gelu -> aw (A of c2)
    const float* bb = params + 4352 + l * 128;
    #pragma unroll
    for (int nt = 0; nt < 8; ++nt) {
      int col = nt * 16 + l16; float bv = bb[col];
      #pragma unroll
      for (int r = 0; r < 4; ++r) {
        float v = acc[nt][r] + bv;
        v = 0.5f * v * (1.f + erff(v * 0.70710678118f));
        aw[(quad * 4 + r) * 136 + col] = __float2bfloat16(v);
      }
    }
  }
  readA(aw, a, quad, l16);
  zero8(acc); mfma_stage(a, w, acc);
  epi_addx(acc, params + 4864 + l * 128, xr, l16);                 // x += c2
  if (l == 3) {
    int f = *flagp;
    const float* ls = params + 1664;
    float s8[8];
    #pragma unroll
    for (int nt = 0; nt < 8; ++nt) s8[nt] = ls[nt * 16 + l16];
    #pragma unroll
    for (int r = 0; r < 4; ++r) {
      float ss = 0.f;
      #pragma unroll
      for (int nt = 0; nt < 8; ++nt) ss += xr[nt][r] * xr[nt][r];
      ss += __shfl_xor(ss, 1); ss += __shfl_xor(ss, 2);
      ss += __shfl_xor(ss, 4); ss += __shfl_xor(ss, 8);
      float rs = rsqrtf(ss * (1.f / 128.f) + 1e-8f);
      #pragma unroll
      for (int nt = 0; nt < 8; ++nt) {
        size_t off = (size_t)(row0 + quad * 4 + r) * 128 + nt * 16 + l16;
        float o = xr[nt][r] * rs * s8[nt];
        if (f) ((float*)dout)[off] = o; else ((unsigned short*)dout)[off] = bfb(o);
      }
    }
    return;
  }
  #pragma unroll
  for (int nt = 0; nt < 8; ++nt)
    #pragma unroll
    for (int r = 0; r < 4; ++r)
      xg[(size_t)(row0 + quad * 4 + r) * 128 + nt * 16 + l16] = xr[nt][r];
  qkvu_stages(xr, aw, wT, params, l + 1, Ug, Qg, Kg, VTg, row0, quad, l16);
}

// ---------------- HSTU flash: pipelined, barrier-free K-loop ----------------
__device__ inline void fk_loadK(const bf16* kbase, bf16x8 (&kf)[2][4], int quad, int l16) {
  #pragma unroll
  for (int kk = 0; kk < 2; ++kk)
    #pragma unroll
    for (int nt = 0; nt < 4; ++nt)
      kf[kk][nt] = *(const bf16x8*)(kbase + (size_t)(nt * 16 + l16) * 128 + kk * 32 + quad * 8);
}

__device__ inline void flash_body(int kt, int ntile, const bf16* kga, const bf16* vba,
    const bf16x8 (&qf)[2][2], const bf16x8 (&kc)[2][4], bf16x8 (&kn)[2][4],
    f32x4 (&oacc)[2][4], f32x4 (&dacc)[2], const bf16x8& onesf,
    bf16* sm, int r0, int quad, int l16) {
  int s0 = kt * 64;
  // V frags issued early (consumed after silu)
  bf16x8 vf[2][4];
  #pragma unroll
  for (int kk = 0; kk < 2; ++kk)
    #pragma unroll
    for (int nt = 0; nt < 4; ++nt)
      vf[kk][nt] = *(const bf16x8*)(vba + (size_t)(nt * 16 + l16) * 2048 + s0 + kk * 32 + quad * 8);
  // S = Q K^T (Q pre-scaled by 1/8)
  f32x4 sacc[2][4] = {};
  #pragma unroll
  for (int kk = 0; kk < 2; ++kk)
    #pragma unroll
    for (int nt = 0; nt < 4; ++nt) {
      sacc[0][nt] = __builtin_amdgcn_mfma_f32_16x16x32_bf16(qf[0][kk], kc[kk][nt], sacc[0][nt], 0, 0, 0);
      sacc[1][nt] = __builtin_amdgcn_mfma_f32_16x16x32_bf16(qf[1][kk], kc[kk][nt], sacc[1][nt], 0, 0, 0);
    }
  // prefetch K for kt+2 (ping-pong buffer)
  if (kt + 2 < ntile) fk_loadK(kga + (size_t)(s0 + 128) * 128, kn, quad, l16);
  // silu + causal clamp -> sm (wave-private; in-wave lgkm ordering)
  #pragma unroll
  for (int mi = 0; mi < 2; ++mi) {
    int trow = r0 + mi * 16 + quad * 4;
    #pragma unroll
    for (int nt = 0; nt < 4; ++nt) {
      int sc = s0 + nt * 16 + l16;
      #pragma unroll
      for (int r = 0; r < 4; ++r) {
        float v = sacc[mi][nt][r];
        float aa = (sc <= trow + r && v > 0.f) ? v / (1.f + __expf(-v)) : 0.f;
        sm[(mi * 16 + quad * 4 + r) * 72 + nt * 16 + l16] = __float2bfloat16(aa);
      }
    }
  }
  // O += S@V; rowsum via ones-column MFMA
  #pragma unroll
  for (int kk = 0; kk < 2; ++kk) {
    bf16x8 af0 = *(const bf16x8*)&sm[l16 * 72 + kk * 32 + quad * 8];
    bf16x8 af1 = *(const bf16x8*)&sm[(16 + l16) * 72 + kk * 32 + quad * 8];
    #pragma unroll
    for (int nt = 0; nt < 4; ++nt) {
      oacc[0][nt] = __builtin_amdgcn_mfma_f32_16x16x32_bf16(af0, vf[kk][nt], oacc[0][nt], 0, 0, 0);
      oacc[1][nt] = __builtin_amdgcn_mfma_f32_16x16x32_bf16(af1, vf[kk][nt], oacc[1][nt], 0, 0, 0);
    }
    dacc[0] = __builtin_amdgcn_mfma_f32_16x16x32_bf16(af0, onesf, dacc[0], 0, 0, 0);
    dacc[1] = __builtin_amdgcn_mfma_f32_16x16x32_bf16(af1, onesf, dacc[1], 0, 0, 0);
  }
}

// grid (64, 16), block 128 = 2 parity waves over one 32-row q-tile.
__global__ __launch_bounds__(128, 2) void flash_k(const bf16* __restrict__ Qg,
    const bf16* __restrict__ Kg, const bf16* __restrict__ VTg, float* __restrict__ avg) {
  __shared__ __align__(16) bf16 smem[2 * 2304];   // 2 waves x 32x72; merge overlays
  int q32 = 63 - (int)blockIdx.x;                 // longest-work blocks dispatch first
  int bh = blockIdx.y, b = bh >> 1, h = bh & 1;
  int tid = threadIdx.x, p = tid >> 6, lane = tid & 63, quad = lane >> 4, l16 = lane & 15;
  int r0 = q32 * 32;
  bf16* sm = smem + p * 2304;
  const bf16* kga = Kg + (size_t)b * 2048 * 128 + h * 64;
  const bf16* vba = VTg + (size_t)bh * 64 * 2048;
  const bf16* qbase = Qg + ((size_t)b * 2048 + r0) * 128 + h * 64;
  bf16x8 qf[2][2];
  #pragma unroll
  for (int mi = 0; mi < 2; ++mi)
    #pragma unroll
    for (int kk = 0; kk < 2; ++kk)
      qf[mi][kk] = *(const bf16x8*)(qbase + (size_t)(mi * 16 + l16) * 128 + kk * 32 + quad * 8);
  bf16x8 onesf;
  #pragma unroll
  for (int j = 0; j < 8; ++j) onesf[j] = (l16 == 0) ? (__bf16)1.0f : (__bf16)0.0f;
  f32x4 oacc[2][4] = {};
  f32x4 dacc[2] = {};
  int ntile = q32 / 2 + 1;
  bf16x8 kA[2][4], kB[2][4];
  int kt = p;
  if (kt < ntile) {
    fk_loadK(kga + (size_t)kt * 64 * 128, kA, quad, l16);
    while (true) {
      flash_body(kt, ntile, kga, vba, qf, kA, kB, oacc, dacc, onesf, sm, r0, quad, l16);
      kt += 2;
      if (kt >= ntile) break;
      flash_body(kt, ntile, kga, vba, qf, kB, kA, oacc, dacc, onesf, sm, r0, quad, l16);
      kt += 2;
      if (kt >= ntile) break;
    }
  }
  __syncthreads();
  float* mo = (float*)smem;          // 32 x 64
  float* md = mo + 2048;             // 32 row sums
  if (p == 1) {
    #pragma unroll
    for (int mi = 0; mi < 2; ++mi) {
      #pragma unroll
      for (int nt = 0; nt < 4; ++nt)
        #pragma unroll
        for (int r = 0; r < 4; ++r)
          mo[(mi * 16 + quad * 4 + r) * 64 + nt * 16 + l16] = oacc[mi][nt][r];
      if (l16 == 0) {
        #pragma unroll
        for (int r = 0; r < 4; ++r) md[mi * 16 + quad * 4 + r] = dacc[mi][r];
      }
    }
  }
  __syncthreads();
  if (p == 0) {
    #pragma unroll
    for (int mi = 0; mi < 2; ++mi) {
      #pragma unroll
      for (int r = 0; r < 4; ++r) {
        float dn = __shfl(dacc[mi][r], quad << 4) + md[mi * 16 + quad * 4 + r];
        float inv = (dn > 1e-12f) ? 1.f / (dn + 1e-8f) : 0.f;
        int row = r0 + mi * 16 + quad * 4 + r;
        #pragma unroll
        for (int nt = 0; nt < 4; ++nt) {
          float o = (oacc[mi][nt][r] + mo[(mi * 16 + quad * 4 + r) * 64 + nt * 16 + l16]) * inv;
          avg[((size_t)b * 2048 + row) * 128 + h * 64 + nt * 16 + l16] = o;
        }
      }
    }
  }
}

// ---------------- launch ----------------
extern "C" void kernel_launch(void* const* d_in, const int* in_sizes, int n_in,
                              void* d_out, int out_size, void* d_ws, size_t ws_size,
                              hipStream_t stream) {
  const int* seqs = (const int*)d_in[0];
  const void* item = d_in[2];
  const void* pos  = d_in[3];

  float* params = (float*)d_ws;
  int* flagp = (int*)((char*)d_ws + 24 * 1024);
  char* base = (char*)d_ws + 32 * 1024;
  const size_t MB = 1024 * 1024;
  float* x   = (float*)base;                 // 8 MB fp32 residual
  float* av  = (float*)(base + 8 * MB);      // 8 MB fp32 attention out
  bf16* Ug   = (bf16*)(base + 16 * MB);      // 4 MB
  bf16* Qg   = (bf16*)(base + 20 * MB);      // 4 MB (pre-scaled by 1/8)
  bf16* Kg   = (bf16*)(base + 24 * MB);      // 4 MB
  bf16* VTg  = (bf16*)(base + 28 * MB);      // 4 MB  [bh][hd][t]
  bf16* wT   = (bf16*)(base + 32 * MB);      // 28 * 16384 bf16 = 896 KB

  PPtrs pp;
  pp.p[0] = d_in[4];  pp.p[1] = d_in[5];  pp.p[2] = d_in[16]; pp.p[3] = d_in[17];
  pp.p[4] = d_in[22]; pp.p[5] = d_in[7];  pp.p[6] = d_in[9];  pp.p[7] = d_in[11];
  pp.p[8] = d_in[13]; pp.p[9] = d_in[15]; pp.p[10] = d_in[19]; pp.p[11] = d_in[21];
  detect_convert_k<<<1, 256, 0, stream>>>(item, pp, params, flagp);

  WPtrs wp;
  wp.p[0] = d_in[6]; wp.p[1] = d_in[8]; wp.p[2] = d_in[10]; wp.p[3] = d_in[12];
  wp.p[4] = d_in[14]; wp.p[5] = d_in[18]; wp.p[6] = d_in[20];
  transpose_w_k<<<dim3(4, 7), 256, 0, stream>>>(wp, wT, flagp);

  pre_k<<<M / 64, 256, 0, stream>>>(seqs, item, pos, wT, params, x, Ug, Qg, Kg, VTg, flagp);

  for (int l = 0; l < 4; ++l) {
    flash_k<<<dim3(64, 16), 128, 0, stream>>>(Qg, Kg, VTg, av);
    post_k<<<M / 64, 256, 0, stream>>>(l, x, av, Ug, Qg, Kg, VTg, wT, params, d_out, flagp);
  }
}